// Round 2
// baseline (327.563 us; speedup 1.0000x reference)
//
#include <hip/hip_runtime.h>

// CTC forward NLL (warp-ctc semantics), B=32 T=1024 V=1024 L=128, S=2L+1=257.
// Phase 1: per-(b,t) row logsumexp over V + gather of the 129 needed labels
//          (blank + L targets), stored in base-2 log domain (native exp2/log2).
// Phase 2: one wave per batch element, 4 s-slots per lane (+1 on lane 63),
//          sequential alpha recursion over t with a single shfl_up per step.

#define NEG   (-1e30f)
#define LOG2E 1.4426950408889634f
#define LN2   0.6931471805599453f

constexpr int B = 32, T = 1024, V = 1024, L = 128;
constexpr int S = 2 * L + 1;   // 257
constexpr int LPS = 132;       // padded row stride (floats) for lp2 rows; 129 used

// native hw transcendentals: v_exp_f32 = 2^x, v_log_f32 = log2(x)
__device__ inline float fexp2(float x) { return __builtin_amdgcn_exp2f(x); }
__device__ inline float flog2(float x) { return __builtin_amdgcn_logf(x); }

__device__ inline float lse2_2(float a, float b) {
    float m = fmaxf(a, b);
    return m + flog2(fexp2(a - m) + fexp2(b - m));
}
__device__ inline float lse2_3(float a, float b, float c) {
    float m = fmaxf(fmaxf(a, b), c);
    return m + flog2(fexp2(a - m) + fexp2(b - m) + fexp2(c - m));
}

// ---- Kernel 1: log-softmax denominator + label gather -----------------------
// grid = B*T blocks, 256 threads. Each block owns one 1024-float row.
__global__ __launch_bounds__(256) void k_lse_gather(
    const float* __restrict__ logits, const int* __restrict__ targets,
    float* __restrict__ lp2)
{
    const int row = blockIdx.x;          // b*T + t
    const int b   = row >> 10;           // T = 1024
    const float* x = logits + (size_t)row * V;
    const int tid = threadIdx.x;

    float4 v = reinterpret_cast<const float4*>(x)[tid];   // coalesced 4 KB row
    float m = fmaxf(fmaxf(v.x, v.y), fmaxf(v.z, v.w));
    #pragma unroll
    for (int off = 32; off; off >>= 1) m = fmaxf(m, __shfl_xor(m, off));

    __shared__ float red[8];
    const int lane = tid & 63, wv = tid >> 6;
    if (lane == 0) red[wv] = m;
    __syncthreads();
    m = fmaxf(fmaxf(red[0], red[1]), fmaxf(red[2], red[3]));

    float s = fexp2((v.x - m) * LOG2E) + fexp2((v.y - m) * LOG2E)
            + fexp2((v.z - m) * LOG2E) + fexp2((v.w - m) * LOG2E);
    #pragma unroll
    for (int off = 32; off; off >>= 1) s += __shfl_xor(s, off);
    if (lane == 0) red[4 + wv] = s;
    __syncthreads();
    s = red[4] + red[5] + red[6] + red[7];

    // lp2[j] = (x[lab_j] - lse_e) * log2e = x[lab_j]*log2e - (m*log2e + log2(s))
    const float lse2 = m * LOG2E + flog2(s);
    if (tid <= L) {
        const int lab = (tid == 0) ? 0 : targets[b * L + tid - 1];
        lp2[(size_t)row * LPS + tid] = x[lab] * LOG2E - lse2;
    }
}

// ---- Kernel 2: alpha recursion ----------------------------------------------
// grid = B blocks, 64 threads (one wave). Lane l owns s = 4l..4l+3; lane 63
// additionally owns s = 256. Only cross-lane value per step: alpha[4l-1].
__global__ __launch_bounds__(64) void k_ctc_alpha(
    const float* __restrict__ lp2, const int* __restrict__ targets,
    const int* __restrict__ loglen, const int* __restrict__ tgtlen,
    float* __restrict__ out)
{
    const int b  = blockIdx.x;
    const int l  = threadIdx.x;          // lane 0..63
    const int len = loglen[b];           // in [512, 1024]
    const int tl  = tgtlen[b];           // in [64, 128]
    const int Sv  = 2 * tl + 1;          // valid s: s < Sv

    // loop-invariant skip masks (odd slots only):
    //   slot1: s=4l+1, labels tgt[2l] vs tgt[2l-1]
    //   slot3: s=4l+3, labels tgt[2l+1] vs tgt[2l]
    const int* tg = targets + b * L;
    const int t2l   = tg[2 * l];                       // 2l <= 126 < L
    const int t2lm1 = (l > 0) ? tg[2 * l - 1] : -3;
    const int t2lp1 = tg[2 * l + 1];                   // 2l+1 <= 127 < L
    const bool cs1 = (t2l != t2lm1);
    const bool cs3 = (t2lp1 != t2l);

    const bool v0 = (4 * l     < Sv);
    const bool v1 = (4 * l + 1 < Sv);
    const bool v2 = (4 * l + 2 < Sv);
    const bool v3 = (4 * l + 3 < Sv);
    const bool v4 = (l == 63) && (256 < Sv);

    // t = 0 init: alpha[0] = lp(0,blank), alpha[1] = lp(0,label0), rest NEG
    const float* row0 = lp2 + (size_t)(b * T) * LPS;
    float A0 = (l == 0) ? row0[0] : NEG;
    float A1 = (l == 0) ? row0[1] : NEG;
    float A2 = NEG, A3 = NEG, A4 = NEG;

    // prefetch row t=1
    const float* r1 = lp2 + (size_t)(b * T + 1) * LPS;
    float lpb = r1[0];
    float lp1 = r1[2 * l + 1];
    float lp3 = r1[2 * l + 2];

    for (int t = 1; t < len; ++t) {
        const float clpb = lpb, clp1 = lp1, clp3 = lp3;
        if (t + 1 < len) {                       // prefetch t+1
            const float* r = lp2 + (size_t)(b * T + t + 1) * LPS;
            lpb = r[0]; lp1 = r[2 * l + 1]; lp3 = r[2 * l + 2];
        }
        float p3 = __shfl_up(A3, 1);             // alpha[4l-1]
        if (l == 0) p3 = NEG;

        const float n0 = lse2_2(A0, p3)                        + clpb; // s even
        const float n1 = lse2_3(A1, A0, cs1 ? p3 : NEG)        + clp1; // s odd
        const float n2 = lse2_2(A2, A1)                        + clpb; // s even
        const float n3 = lse2_3(A3, A2, cs3 ? A1 : NEG)        + clp3; // s odd
        const float n4 = lse2_2(A4, A3)                        + clpb; // s=256

        A0 = v0 ? n0 : NEG;
        A1 = v1 ? n1 : NEG;
        A2 = v2 ? n2 : NEG;
        A3 = v3 ? n3 : NEG;
        A4 = v4 ? n4 : NEG;
    }

    __shared__ float alpha[S];
    alpha[4 * l + 0] = A0;
    alpha[4 * l + 1] = A1;
    alpha[4 * l + 2] = A2;
    alpha[4 * l + 3] = A3;
    if (l == 63) alpha[256] = A4;
    __syncthreads();

    if (l == 0) {
        const float ea = alpha[2 * tl];
        const float eb = alpha[2 * tl - 1];
        const float m  = fmaxf(ea, eb);
        out[b] = -LN2 * (m + flog2(fexp2(ea - m) + fexp2(eb - m)));
    }
}

extern "C" void kernel_launch(void* const* d_in, const int* in_sizes, int n_in,
                              void* d_out, int out_size, void* d_ws, size_t ws_size,
                              hipStream_t stream) {
    const float* logits  = (const float*)d_in[0];
    const int*   targets = (const int*)d_in[1];
    const int*   loglen  = (const int*)d_in[2];
    const int*   tgtlen  = (const int*)d_in[3];
    float* out = (float*)d_out;
    float* lp2 = (float*)d_ws;   // needs B*T*LPS*4 = 17.3 MB

    k_lse_gather<<<B * T, 256, 0, stream>>>(logits, targets, lp2);
    k_ctc_alpha<<<B, 64, 0, stream>>>(lp2, targets, loglen, tgtlen, out);
}

// Round 3
// 309.700 us; speedup vs baseline: 1.0577x; 1.0577x over previous
//
#include <hip/hip_runtime.h>

// CTC forward NLL (warp-ctc semantics), B=32 T=1024 V=1024 L=128, S=2L+1=257.
// Phase 1: per-(b,t) row logsumexp over V + gather of the 129 needed labels,
//          stored base-2 log domain. Row layout: [blank, pad, lab0, lab1, ...]
//          so each lane's (lab[2l], lab[2l+1]) pair is one aligned float2.
// Phase 2: one wave per batch element, 4 s-slots per lane (+1 on lane 63),
//          sequential recursion over t, single shfl_up per step, and a
//          PF-deep register prefetch ring to hide L3/HBM latency.

#define NEG   (-1e30f)
#define LOG2E 1.4426950408889634f
#define LN2   0.6931471805599453f

constexpr int B = 32, T = 1024, V = 1024, L = 128;
constexpr int S = 2 * L + 1;   // 257
constexpr int LPS = 132;       // padded row stride (floats); 130 used
constexpr int PF = 12;         // prefetch depth (steps ahead); PF < 512 <= len

// native hw transcendentals: v_exp_f32 = 2^x, v_log_f32 = log2(x)
__device__ inline float fexp2(float x) { return __builtin_amdgcn_exp2f(x); }
__device__ inline float flog2(float x) { return __builtin_amdgcn_logf(x); }

__device__ inline float lse2_2(float a, float b) {
    float m = fmaxf(a, b);
    return m + flog2(fexp2(a - m) + fexp2(b - m));
}
__device__ inline float lse2_3(float a, float b, float c) {
    float m = fmaxf(fmaxf(a, b), c);
    return m + flog2(fexp2(a - m) + fexp2(b - m) + fexp2(c - m));
}

// ---- Kernel 1: log-softmax denominator + label gather -----------------------
__global__ __launch_bounds__(256) void k_lse_gather(
    const float* __restrict__ logits, const int* __restrict__ targets,
    float* __restrict__ lp2)
{
    const int row = blockIdx.x;          // b*T + t
    const int b   = row >> 10;           // T = 1024
    const float* x = logits + (size_t)row * V;
    const int tid = threadIdx.x;

    float4 v = reinterpret_cast<const float4*>(x)[tid];   // coalesced 4 KB row
    float m = fmaxf(fmaxf(v.x, v.y), fmaxf(v.z, v.w));
    #pragma unroll
    for (int off = 32; off; off >>= 1) m = fmaxf(m, __shfl_xor(m, off));

    __shared__ float red[8];
    const int lane = tid & 63, wv = tid >> 6;
    if (lane == 0) red[wv] = m;
    __syncthreads();
    m = fmaxf(fmaxf(red[0], red[1]), fmaxf(red[2], red[3]));

    float s = fexp2((v.x - m) * LOG2E) + fexp2((v.y - m) * LOG2E)
            + fexp2((v.z - m) * LOG2E) + fexp2((v.w - m) * LOG2E);
    #pragma unroll
    for (int off = 32; off; off >>= 1) s += __shfl_xor(s, off);
    if (lane == 0) red[4 + wv] = s;
    __syncthreads();
    s = red[4] + red[5] + red[6] + red[7];

    const float lse2 = m * LOG2E + flog2(s);
    if (tid <= L) {
        // offset 0 = blank, offset 2+j = target j (offset 1 = pad, for alignment)
        const int lab = (tid == 0) ? 0 : targets[b * L + tid - 1];
        const int off = (tid == 0) ? 0 : tid + 1;
        lp2[(size_t)row * LPS + off] = x[lab] * LOG2E - lse2;
    }
}

// ---- Kernel 2: alpha recursion ----------------------------------------------
__global__ __launch_bounds__(64) void k_ctc_alpha(
    const float* __restrict__ lp2, const int* __restrict__ targets,
    const int* __restrict__ loglen, const int* __restrict__ tgtlen,
    float* __restrict__ out)
{
    const int b  = blockIdx.x;
    const int l  = threadIdx.x;          // lane 0..63
    const int len = loglen[b];           // in [512, 1024]
    const int tl  = tgtlen[b];           // in [64, 128]
    const int Sv  = 2 * tl + 1;          // valid s: s < Sv

    const int* tg = targets + b * L;
    const int t2l   = tg[2 * l];
    const int t2lm1 = (l > 0) ? tg[2 * l - 1] : -3;
    const int t2lp1 = tg[2 * l + 1];
    const bool cs1 = (t2l != t2lm1);     // skip into s=4l+1
    const bool cs3 = (t2lp1 != t2l);     // skip into s=4l+3

    const bool v0 = (4 * l     < Sv);
    const bool v1 = (4 * l + 1 < Sv);
    const bool v2 = (4 * l + 2 < Sv);
    const bool v3 = (4 * l + 3 < Sv);
    const bool v4 = (l == 63) && (256 < Sv);

    // t = 0 init
    const float* row0 = lp2 + (size_t)(b * T) * LPS;
    float A0 = (l == 0) ? row0[0] : NEG;   // alpha[0] = lp(0, blank)
    float A1 = (l == 0) ? row0[2] : NEG;   // alpha[1] = lp(0, label 0)
    float A2 = NEG, A3 = NEG, A4 = NEG;

    // prefetch ring: slot i holds row (tb + i) of the current main-loop block
    float plb[PF];  float2 plq[PF];
    #pragma unroll
    for (int i = 0; i < PF; ++i) {
        const float* r = lp2 + (size_t)(b * T + 1 + i) * LPS;   // 1+i <= PF < len
        plb[i] = r[0];
        plq[i] = *reinterpret_cast<const float2*>(r + 2 + 2 * l);
    }

    #define CTC_STEP(CLPB, CLP1, CLP3)                                   \
    {                                                                     \
        float p3 = __shfl_up(A3, 1);                                      \
        if (l == 0) p3 = NEG;                                             \
        const float n0 = lse2_2(A0, p3)                 + (CLPB);         \
        const float n1 = lse2_3(A1, A0, cs1 ? p3 : NEG) + (CLP1);         \
        const float n2 = lse2_2(A2, A1)                 + (CLPB);         \
        const float n3 = lse2_3(A3, A2, cs3 ? A1 : NEG) + (CLP3);         \
        const float n4 = lse2_2(A4, A3)                 + (CLPB);         \
        A0 = v0 ? n0 : NEG;                                               \
        A1 = v1 ? n1 : NEG;                                               \
        A2 = v2 ? n2 : NEG;                                               \
        A3 = v3 ? n3 : NEG;                                               \
        A4 = v4 ? n4 : NEG;                                               \
    }

    for (int tb = 1; tb < len; tb += PF) {
        #pragma unroll
        for (int i = 0; i < PF; ++i) {
            const int tc = tb + i;
            if (tc < len) {                       // wave-uniform guard
                const float clpb = plb[i];
                const float clp1 = plq[i].x, clp3 = plq[i].y;
                const int tn = (tc + PF <= T - 1) ? tc + PF : T - 1;  // clamp
                const float* r = lp2 + (size_t)(b * T + tn) * LPS;
                plb[i] = r[0];
                plq[i] = *reinterpret_cast<const float2*>(r + 2 + 2 * l);
                CTC_STEP(clpb, clp1, clp3);
            }
        }
    }
    #undef CTC_STEP

    __shared__ float alpha[S];
    alpha[4 * l + 0] = A0;
    alpha[4 * l + 1] = A1;
    alpha[4 * l + 2] = A2;
    alpha[4 * l + 3] = A3;
    if (l == 63) alpha[256] = A4;
    __syncthreads();

    if (l == 0) {
        const float ea = alpha[2 * tl];
        const float eb = alpha[2 * tl - 1];
        const float m  = fmaxf(ea, eb);
        out[b] = -LN2 * (m + flog2(fexp2(ea - m) + fexp2(eb - m)));
    }
}

extern "C" void kernel_launch(void* const* d_in, const int* in_sizes, int n_in,
                              void* d_out, int out_size, void* d_ws, size_t ws_size,
                              hipStream_t stream) {
    const float* logits  = (const float*)d_in[0];
    const int*   targets = (const int*)d_in[1];
    const int*   loglen  = (const int*)d_in[2];
    const int*   tgtlen  = (const int*)d_in[3];
    float* out = (float*)d_out;
    float* lp2 = (float*)d_ws;   // needs B*T*LPS*4 = 17.3 MB

    k_lse_gather<<<B * T, 256, 0, stream>>>(logits, targets, lp2);
    k_ctc_alpha<<<B, 64, 0, stream>>>(lp2, targets, loglen, tgtlen, out);
}

// Round 4
// 214.897 us; speedup vs baseline: 1.5243x; 1.4412x over previous
//
#include <hip/hip_runtime.h>

// CTC forward NLL (warp-ctc semantics), B=32 T=1024 V=1024 L=128, S=2L+1=257.
// Phase 1: per-(b,t) row logsumexp over V; writes blank lp to lpB[B*T] and the
//          128 label lps to packed 128-float rows lpQ[(b*T+t)*128 + j].
// Phase 2: one wave per batch element, 4 s-slots per lane (+1 on lane 63).
//          32-timestep LDS double-buffer staged with async global_load_lds;
//          per-step LDS reads through a depth-2 named-register ring; the
//          cross-lane alpha[4l-1] shift uses DPP wave_shr:1 (no ds_bpermute).

#define NEG   (-1e30f)
#define LOG2E 1.4426950408889634f
#define LN2   0.6931471805599453f

constexpr int B = 32, T = 1024, V = 1024, L = 128;
constexpr int S = 2 * L + 1;   // 257
constexpr int TS = 32;         // timesteps staged per LDS block

// native hw transcendentals: v_exp_f32 = 2^x, v_log_f32 = log2(x)
__device__ inline float fexp2(float x) { return __builtin_amdgcn_exp2f(x); }
__device__ inline float flog2(float x) { return __builtin_amdgcn_logf(x); }

__device__ inline float lse2_2(float a, float b) {
    float m = fmaxf(a, b);
    return m + flog2(fexp2(a - m) + fexp2(b - m));
}
__device__ inline float lse2_3(float a, float b, float c) {
    float m = fmaxf(fmaxf(a, b), c);
    return m + flog2(fexp2(a - m) + fexp2(b - m) + fexp2(c - m));
}

// lane l <- lane l-1, lane 0 <- NEG.  DPP wave_shr:1 = 0x138 (gfx9/CDNA family).
__device__ inline float dpp_shr1_neg(float x) {
    int r = __builtin_amdgcn_update_dpp(__float_as_int(NEG), __float_as_int(x),
                                        0x138, 0xF, 0xF, false);
    return __int_as_float(r);
}

// ---- Kernel 1: log-softmax denominator + label gather -----------------------
__global__ __launch_bounds__(256) void k_lse_gather(
    const float* __restrict__ logits, const int* __restrict__ targets,
    float* __restrict__ lpQ, float* __restrict__ lpB)
{
    const int row = blockIdx.x;          // b*T + t
    const int b   = row >> 10;           // T = 1024
    const float* x = logits + (size_t)row * V;
    const int tid = threadIdx.x;

    float4 v = reinterpret_cast<const float4*>(x)[tid];   // coalesced 4 KB row
    float m = fmaxf(fmaxf(v.x, v.y), fmaxf(v.z, v.w));
    #pragma unroll
    for (int off = 32; off; off >>= 1) m = fmaxf(m, __shfl_xor(m, off));

    __shared__ float red[8];
    const int lane = tid & 63, wv = tid >> 6;
    if (lane == 0) red[wv] = m;
    __syncthreads();
    m = fmaxf(fmaxf(red[0], red[1]), fmaxf(red[2], red[3]));

    float s = fexp2((v.x - m) * LOG2E) + fexp2((v.y - m) * LOG2E)
            + fexp2((v.z - m) * LOG2E) + fexp2((v.w - m) * LOG2E);
    #pragma unroll
    for (int off = 32; off; off >>= 1) s += __shfl_xor(s, off);
    if (lane == 0) red[4 + wv] = s;
    __syncthreads();
    s = red[4] + red[5] + red[6] + red[7];

    const float lse2 = m * LOG2E + flog2(s);
    if (tid == 0) {
        lpB[row] = x[0] * LOG2E - lse2;                       // blank (label 0)
    } else if (tid <= L) {
        const int lab = targets[b * L + tid - 1];
        lpQ[(size_t)row * 128 + tid - 1] = x[lab] * LOG2E - lse2;
    }
}

// ---- Kernel 2: alpha recursion ----------------------------------------------
__global__ __launch_bounds__(64) void k_ctc_alpha(
    const float* __restrict__ lpQ, const float* __restrict__ lpB,
    const int* __restrict__ targets, const int* __restrict__ loglen,
    const int* __restrict__ tgtlen, float* __restrict__ out)
{
    const int b  = blockIdx.x;
    const int l  = threadIdx.x;          // lane 0..63
    const int len = loglen[b];           // in [512, 1024]
    const int tl  = tgtlen[b];           // in [64, 128]
    const int Sv  = 2 * tl + 1;          // valid s: s < Sv

    const int* tg = targets + b * L;
    const int t2l   = tg[2 * l];
    const int t2lm1 = (l > 0) ? tg[2 * l - 1] : -3;
    const int t2lp1 = tg[2 * l + 1];
    const bool cs1 = (t2l != t2lm1);     // skip into s=4l+1
    const bool cs3 = (t2lp1 != t2l);     // skip into s=4l+3

    const bool v0 = (4 * l     < Sv);
    const bool v1 = (4 * l + 1 < Sv);
    const bool v2 = (4 * l + 2 < Sv);
    const bool v3 = (4 * l + 3 < Sv);
    const bool v4 = (l == 63) && (256 < Sv);

    // t = 0 init
    float A0 = (l == 0) ? lpB[(size_t)b * T] : NEG;
    float A1 = (l == 0) ? lpQ[(size_t)b * T * 128] : NEG;
    float A2 = NEG, A3 = NEG, A4 = NEG;
    float p3 = NEG;                      // alpha[4l-1] from previous step

    __shared__ __align__(16) float sQ[2][TS][128];   // 32 KB
    __shared__ __align__(16) float sB[2][64];
    __shared__ float alpha[S];

    // per-lane global base for the staged label-pair loads
    const float* gQ = lpQ + (size_t)b * T * 128 + (l & 31) * 4;

    // STAGE(buf, t0): rows t0..t0+TS-1 (clamped to T-1) -> sQ[buf], sB[buf].
    // LDS dest is wave-uniform base + lane*size (linear); global src per-lane.
    #define STAGE(buf, t0)                                                     \
    {                                                                          \
        _Pragma("unroll")                                                      \
        for (int c = 0; c < 16; ++c) {                                         \
            const int r  = (t0) + 2 * c + (l >> 5);                            \
            const int rc = (r < T) ? r : (T - 1);                              \
            const float* gp = gQ + (size_t)rc * 128;                           \
            __builtin_amdgcn_global_load_lds(                                  \
                (const __attribute__((address_space(1))) void*)gp,             \
                (__attribute__((address_space(3))) void*)&sQ[buf][2 * c][0],   \
                16, 0, 0);                                                     \
        }                                                                      \
        {                                                                      \
            const int r  = (t0) + l;                                           \
            const int rc = (r < T) ? r : (T - 1);                              \
            const float* gp = lpB + (size_t)b * T + rc;                        \
            __builtin_amdgcn_global_load_lds(                                  \
                (const __attribute__((address_space(1))) void*)gp,             \
                (__attribute__((address_space(3))) void*)&sB[buf][0],          \
                4, 0, 0);                                                      \
        }                                                                      \
    }

    STAGE(0, 1);                         // prologue: rows 1..32 -> buf 0
    int cb = 0;

    for (int tb = 1; tb < len; tb += TS) {
        // current buffer's staging (issued last iteration) must have landed
        asm volatile("s_waitcnt vmcnt(0)" ::: "memory");
        STAGE(cb ^ 1, tb + TS);          // async prefetch of next block

        // depth-2 named-register ring fed from LDS
        float2 q0 = *reinterpret_cast<const float2*>(&sQ[cb][0][2 * l]);
        float  b0 = sB[cb][0];
        float2 q1 = *reinterpret_cast<const float2*>(&sQ[cb][1][2 * l]);
        float  b1 = sB[cb][1];

        #pragma unroll
        for (int i = 0; i < TS; ++i) {
            if (tb + i < len) {          // wave-uniform guard (freeze past len)
                const float clpb = b0, clp1 = q0.x, clp3 = q0.y;
                q0 = q1; b0 = b1;
                if (i + 2 < TS) {
                    q1 = *reinterpret_cast<const float2*>(&sQ[cb][i + 2][2 * l]);
                    b1 = sB[cb][i + 2];
                }
                const float n0 = lse2_2(A0, p3)                 + clpb;
                const float n1 = lse2_3(A1, A0, cs1 ? p3 : NEG) + clp1;
                const float n2 = lse2_2(A2, A1)                 + clpb;
                const float n3 = lse2_3(A3, A2, cs3 ? A1 : NEG) + clp3;
                const float n4 = lse2_2(A4, A3)                 + clpb;
                A0 = v0 ? n0 : NEG;
                A1 = v1 ? n1 : NEG;
                A2 = v2 ? n2 : NEG;
                A3 = v3 ? n3 : NEG;
                A4 = v4 ? n4 : NEG;
                p3 = dpp_shr1_neg(A3);   // alpha[4l-1] for the next step
            }
        }
        cb ^= 1;
    }
    #undef STAGE

    alpha[4 * l + 0] = A0;
    alpha[4 * l + 1] = A1;
    alpha[4 * l + 2] = A2;
    alpha[4 * l + 3] = A3;
    if (l == 63) alpha[256] = A4;
    __syncthreads();

    if (l == 0) {
        const float ea = alpha[2 * tl];
        const float eb = alpha[2 * tl - 1];
        const float m  = fmaxf(ea, eb);
        out[b] = -LN2 * (m + flog2(fexp2(ea - m) + fexp2(eb - m)));
    }
}

extern "C" void kernel_launch(void* const* d_in, const int* in_sizes, int n_in,
                              void* d_out, int out_size, void* d_ws, size_t ws_size,
                              hipStream_t stream) {
    const float* logits  = (const float*)d_in[0];
    const int*   targets = (const int*)d_in[1];
    const int*   loglen  = (const int*)d_in[2];
    const int*   tgtlen  = (const int*)d_in[3];
    float* out = (float*)d_out;
    float* lpQ = (float*)d_ws;                               // B*T*128 floats
    float* lpB = lpQ + (size_t)B * T * 128;                  // B*T floats

    k_lse_gather<<<B * T, 256, 0, stream>>>(logits, targets, lpQ, lpB);
    k_ctc_alpha<<<B, 64, 0, stream>>>(lpQ, lpB, targets, loglen, tgtlen, out);
}

// Round 6
// 95.018 us; speedup vs baseline: 3.4474x; 2.2616x over previous
//
#include <hip/hip_runtime.h>

// CTC forward NLL (warp-ctc semantics), B=32 T=1024 V=1024 L=128, S=2L+1=257.
// Phase 1: per-(b,t) row softmax; stores LINEAR probs: blank prob to pB[B*T],
//          target-label probs to packed rows pQ[(b*T+t)*128 + j], with
//          columns j >= tgtlen[b] ZEROED (kills invalid lattice slots at the
//          source, so the wave-max rescale in phase 2 tracks the valid band).
// Phase 2: one wave per batch element, 4 s-slots per lane (+1 on lane 63).
//          LINEAR-domain recursion (no transcendentals in the step), with a
//          wave-uniform power-of-2 rescale every 8 steps (DPP max-reduce).
//          64-timestep LDS double-buffer via async global_load_lds; 8-deep
//          unconditional register ring for per-step LDS reads; DPP wave_shr:1
//          for the cross-lane alpha[4l-1] term.

#define LOG2E 1.4426950408889634f
#define LN2   0.6931471805599453f

constexpr int B = 32, T = 1024, V = 1024, L = 128;
constexpr int S = 2 * L + 1;   // 257
constexpr int TS = 64;         // timesteps staged per LDS block
constexpr int RD = 8;          // register ring depth

// native hw transcendentals: v_exp_f32 = 2^x, v_log_f32 = log2(x)
__device__ inline float fexp2(float x) { return __builtin_amdgcn_exp2f(x); }
__device__ inline float flog2(float x) { return __builtin_amdgcn_logf(x); }

template<int CTRL>
__device__ inline float dpp_mov(float old_, float x) {
    return __int_as_float(__builtin_amdgcn_update_dpp(
        __float_as_int(old_), __float_as_int(x), CTRL, 0xF, 0xF, false));
}

// ---- Kernel 1: softmax denominator + linear-prob gather ---------------------
__global__ __launch_bounds__(256) void k_lse_gather(
    const float* __restrict__ logits, const int* __restrict__ targets,
    const int* __restrict__ tgtlen,
    float* __restrict__ pQ, float* __restrict__ pB)
{
    const int row = blockIdx.x;          // b*T + t
    const int b   = row >> 10;           // T = 1024
    const float* x = logits + (size_t)row * V;
    const int tid = threadIdx.x;

    float4 v = reinterpret_cast<const float4*>(x)[tid];   // coalesced 4 KB row
    float m = fmaxf(fmaxf(v.x, v.y), fmaxf(v.z, v.w));
    #pragma unroll
    for (int off = 32; off; off >>= 1) m = fmaxf(m, __shfl_xor(m, off));

    __shared__ float red[8];
    const int lane = tid & 63, wv = tid >> 6;
    if (lane == 0) red[wv] = m;
    __syncthreads();
    m = fmaxf(fmaxf(red[0], red[1]), fmaxf(red[2], red[3]));

    float s = fexp2((v.x - m) * LOG2E) + fexp2((v.y - m) * LOG2E)
            + fexp2((v.z - m) * LOG2E) + fexp2((v.w - m) * LOG2E);
    #pragma unroll
    for (int off = 32; off; off >>= 1) s += __shfl_xor(s, off);
    if (lane == 0) red[4 + wv] = s;
    __syncthreads();
    s = red[4] + red[5] + red[6] + red[7];

    const float lse2 = m * LOG2E + flog2(s);   // log2 of softmax denom (shifted)
    if (tid == 0) {
        pB[row] = fexp2(x[0] * LOG2E - lse2);               // blank prob
    } else if (tid <= L) {
        const int j  = tid - 1;
        const int tl = tgtlen[b];
        const int lab = targets[b * L + j];
        // zero columns j >= tl: invalid odd lattice slots get prob 0, so
        // (by induction) all invalid slots stay exactly 0 in phase 2.
        pQ[(size_t)row * 128 + j] =
            (j < tl) ? fexp2(x[lab] * LOG2E - lse2) : 0.0f;
    }
}

// ---- Kernel 2: linear-domain alpha recursion --------------------------------
__global__ __launch_bounds__(64) void k_ctc_alpha(
    const float* __restrict__ pQ, const float* __restrict__ pB,
    const int* __restrict__ targets, const int* __restrict__ loglen,
    const int* __restrict__ tgtlen, float* __restrict__ out)
{
    const int b  = blockIdx.x;
    const int l  = threadIdx.x;          // lane 0..63
    const int len = loglen[b];           // in [512, 1024]
    const int tl  = tgtlen[b];           // in [64, 128]

    const int* tg = targets + b * L;
    const int t2l   = tg[2 * l];
    const int t2lm1 = (l > 0) ? tg[2 * l - 1] : -3;
    const int t2lp1 = tg[2 * l + 1];
    const bool cs1 = (t2l != t2lm1);     // skip into s=4l+1
    const bool cs3 = (t2lp1 != t2l);     // skip into s=4l+3

    // t = 0 init (true scale, Se = 0)
    float A0 = (l == 0) ? pB[(size_t)b * T] : 0.0f;
    float A1 = (l == 0) ? pQ[(size_t)b * T * 128] : 0.0f;
    float A2 = 0.0f, A3 = 0.0f, A4 = 0.0f;
    float p3 = 0.0f;                     // alpha[4l-1] carried from prev step
    int Se = 0;                          // accumulated log2 of removed scale

    __shared__ __align__(16) float sQ[2][TS][128];   // 64 KB
    __shared__ __align__(16) float sB[2][TS];
    __shared__ float alpha[S];

    // per-lane global base for staged label rows
    const float* gQ = pQ + (size_t)b * T * 128 + (l & 31) * 4;

    #define STAGE(buf, t0)                                                     \
    {                                                                          \
        _Pragma("unroll")                                                      \
        for (int c = 0; c < TS / 2; ++c) {                                     \
            const int r  = (t0) + 2 * c + (l >> 5);                            \
            const int rc = (r < T) ? r : (T - 1);                              \
            const float* gp = gQ + (size_t)rc * 128;                           \
            __builtin_amdgcn_global_load_lds(                                  \
                (const __attribute__((address_space(1))) void*)gp,             \
                (__attribute__((address_space(3))) void*)&sQ[buf][2 * c][0],   \
                16, 0, 0);                                                     \
        }                                                                      \
        {                                                                      \
            const int r  = (t0) + l;                                           \
            const int rc = (r < T) ? r : (T - 1);                              \
            const float* gp = pB + (size_t)b * T + rc;                         \
            __builtin_amdgcn_global_load_lds(                                  \
                (const __attribute__((address_space(1))) void*)gp,             \
                (__attribute__((address_space(3))) void*)&sB[buf][0],          \
                4, 0, 0);                                                      \
        }                                                                      \
    }

    float2 q[RD];  float bb[RD];

    #define PRELOAD(cbuf)                                                      \
    {                                                                          \
        _Pragma("unroll")                                                      \
        for (int r = 0; r < RD; ++r) {                                         \
            q[r]  = *reinterpret_cast<const float2*>(&sQ[cbuf][r][2 * l]);     \
            bb[r] = sB[cbuf][r];                                               \
        }                                                                      \
    }

    // one recursion step; ring index and row are compile-time under unroll
    #define STEP(i)                                                            \
    {                                                                          \
        const float pb  = bb[(i) & (RD - 1)];                                  \
        const float p1  = q[(i) & (RD - 1)].x;                                 \
        const float pl3 = q[(i) & (RD - 1)].y;                                 \
        q[(i) & (RD - 1)] = *reinterpret_cast<const float2*>(                  \
            &sQ[cb][((i) + RD) & (TS - 1)][2 * l]);                            \
        bb[(i) & (RD - 1)] = sB[cb][((i) + RD) & (TS - 1)];                    \
        const float n0 = (A0 + p3) * pb;                                       \
        const float n1 = (A1 + A0 + (cs1 ? p3 : 0.0f)) * p1;                   \
        const float n2 = (A2 + A1) * pb;                                       \
        const float n3 = (A3 + A2 + (cs3 ? A1 : 0.0f)) * pl3;                  \
        const float n4 = (A4 + A3) * pb;                                       \
        A0 = n0; A1 = n1; A2 = n2; A3 = n3; A4 = n4;                           \
        p3 = dpp_mov<0x138>(0.0f, A3);     /* wave_shr:1, lane0 <- 0 */        \
    }

    // wave-uniform power-of-2 rescale: normalize max toward 2^96
    #define RESCALE()                                                          \
    {                                                                          \
        float m_ = fmaxf(fmaxf(A0, A1), fmaxf(A2, fmaxf(A3, A4)));             \
        m_ = fmaxf(m_, dpp_mov<0x111>(m_, m_));   /* row_shr:1  */             \
        m_ = fmaxf(m_, dpp_mov<0x112>(m_, m_));   /* row_shr:2  */             \
        m_ = fmaxf(m_, dpp_mov<0x114>(m_, m_));   /* row_shr:4  */             \
        m_ = fmaxf(m_, dpp_mov<0x118>(m_, m_));   /* row_shr:8  */             \
        m_ = fmaxf(m_, dpp_mov<0x142>(m_, m_));   /* row_bcast:15 */           \
        m_ = fmaxf(m_, dpp_mov<0x143>(m_, m_));   /* row_bcast:31 */           \
        const int e = (__builtin_amdgcn_readlane(__float_as_int(m_), 63)       \
                       >> 23) & 0xff;                                          \
        int kb = 350 - e;                  /* scale = 2^(223-e), biased */     \
        if (kb > 254) kb = 254;            /* clamp, self-recovers */          \
        const float sc = __int_as_float(kb << 23);                             \
        A0 *= sc; A1 *= sc; A2 *= sc; A3 *= sc; A4 *= sc; p3 *= sc;            \
        Se -= (kb - 127);                                                      \
    }

    STAGE(0, 1);                         // prologue: rows 1..TS -> buf 0
    int cb = 0;

    int tb = 1;
    for (; tb + TS <= len; tb += TS) {   // full blocks, no per-step guards
        asm volatile("s_waitcnt vmcnt(0)" ::: "memory");
        STAGE(cb ^ 1, tb + TS);
        PRELOAD(cb);
        #pragma unroll
        for (int i = 0; i < TS; ++i) {
            STEP(i);
            if ((i & 7) == 7) RESCALE();
        }
        cb ^= 1;
    }
    if (tb < len) {                      // guarded tail block
        asm volatile("s_waitcnt vmcnt(0)" ::: "memory");
        PRELOAD(cb);
        #pragma unroll
        for (int i = 0; i < TS; ++i) {
            if (tb + i < len) {
                STEP(i);
                if ((i & 7) == 7) RESCALE();
            }
        }
    }
    #undef STEP
    #undef RESCALE
    #undef PRELOAD
    #undef STAGE

    alpha[4 * l + 0] = A0;
    alpha[4 * l + 1] = A1;
    alpha[4 * l + 2] = A2;
    alpha[4 * l + 3] = A3;
    if (l == 63) alpha[256] = A4;
    __syncthreads();

    if (l == 0) {
        const float sum = alpha[2 * tl] + alpha[2 * tl - 1];
        out[b] = -LN2 * (flog2(sum) + (float)Se);
    }
}

extern "C" void kernel_launch(void* const* d_in, const int* in_sizes, int n_in,
                              void* d_out, int out_size, void* d_ws, size_t ws_size,
                              hipStream_t stream) {
    const float* logits  = (const float*)d_in[0];
    const int*   targets = (const int*)d_in[1];
    const int*   loglen  = (const int*)d_in[2];
    const int*   tgtlen  = (const int*)d_in[3];
    float* out = (float*)d_out;
    float* pQ = (float*)d_ws;                                // B*T*128 floats
    float* pB = pQ + (size_t)B * T * 128;                    // B*T floats

    k_lse_gather<<<B * T, 256, 0, stream>>>(logits, targets, tgtlen, pQ, pB);
    k_ctc_alpha<<<B, 64, 0, stream>>>(pQ, pB, targets, loglen, tgtlen, out);
}

// Round 7
// 94.068 us; speedup vs baseline: 3.4822x; 1.0101x over previous
//
#include <hip/hip_runtime.h>

// CTC forward NLL (warp-ctc semantics), B=32 T=1024 V=1024 L=128, S=2L+1=257.
// Phase 1: per-(b,t) row softmax; stores LINEAR probs: blank prob to pB[B*T],
//          target-label probs to packed rows pQ[(b*T+t)*128 + j], with
//          columns j >= tgtlen[b] ZEROED (kills invalid lattice slots at the
//          source, so the wave-max rescale in phase 2 tracks the valid band).
// Phase 2: one wave per batch element, 4 s-slots per lane (+1 on lane 63).
//          LINEAR-domain recursion (no transcendentals in the step);
//          wave-uniform power-of-2 rescale every 8 steps (DPP max-reduce,
//          target 2^120). 64-timestep LDS double-buffer via global_load_lds;
//          8-step GROUP-PHASED double-buffered register loads (group g+1
//          loaded before group g executes -> ~300 cy LDS cover, zero LDS ops
//          inside the step); DPP wave_shr:1 for the cross-lane alpha[4l-1].

#define LOG2E 1.4426950408889634f
#define LN2   0.6931471805599453f

constexpr int B = 32, T = 1024, V = 1024, L = 128;
constexpr int S = 2 * L + 1;   // 257
constexpr int TS = 64;         // timesteps staged per LDS block

// native hw transcendentals: v_exp_f32 = 2^x, v_log_f32 = log2(x)
__device__ inline float fexp2(float x) { return __builtin_amdgcn_exp2f(x); }
__device__ inline float flog2(float x) { return __builtin_amdgcn_logf(x); }

template<int CTRL>
__device__ inline float dpp_mov(float old_, float x) {
    return __int_as_float(__builtin_amdgcn_update_dpp(
        __float_as_int(old_), __float_as_int(x), CTRL, 0xF, 0xF, false));
}

// ---- Kernel 1: softmax denominator + linear-prob gather ---------------------
__global__ __launch_bounds__(256) void k_lse_gather(
    const float* __restrict__ logits, const int* __restrict__ targets,
    const int* __restrict__ tgtlen,
    float* __restrict__ pQ, float* __restrict__ pB)
{
    const int row = blockIdx.x;          // b*T + t
    const int b   = row >> 10;           // T = 1024
    const float* x = logits + (size_t)row * V;
    const int tid = threadIdx.x;

    float4 v = reinterpret_cast<const float4*>(x)[tid];   // coalesced 4 KB row
    float m = fmaxf(fmaxf(v.x, v.y), fmaxf(v.z, v.w));
    #pragma unroll
    for (int off = 32; off; off >>= 1) m = fmaxf(m, __shfl_xor(m, off));

    __shared__ float red[8];
    const int lane = tid & 63, wv = tid >> 6;
    if (lane == 0) red[wv] = m;
    __syncthreads();
    m = fmaxf(fmaxf(red[0], red[1]), fmaxf(red[2], red[3]));

    float s = fexp2((v.x - m) * LOG2E) + fexp2((v.y - m) * LOG2E)
            + fexp2((v.z - m) * LOG2E) + fexp2((v.w - m) * LOG2E);
    #pragma unroll
    for (int off = 32; off; off >>= 1) s += __shfl_xor(s, off);
    if (lane == 0) red[4 + wv] = s;
    __syncthreads();
    s = red[4] + red[5] + red[6] + red[7];

    const float lse2 = m * LOG2E + flog2(s);   // log2 of softmax denom (shifted)
    if (tid == 0) {
        pB[row] = fexp2(x[0] * LOG2E - lse2);               // blank prob
    } else if (tid <= L) {
        const int j  = tid - 1;
        const int tl = tgtlen[b];
        const int lab = targets[b * L + j];
        // zero columns j >= tl: invalid odd lattice slots get prob 0, so
        // (by induction) all invalid slots stay exactly 0 in phase 2.
        pQ[(size_t)row * 128 + j] =
            (j < tl) ? fexp2(x[lab] * LOG2E - lse2) : 0.0f;
    }
}

// ---- Kernel 2: linear-domain alpha recursion --------------------------------
__global__ __launch_bounds__(64) void k_ctc_alpha(
    const float* __restrict__ pQ, const float* __restrict__ pB,
    const int* __restrict__ targets, const int* __restrict__ loglen,
    const int* __restrict__ tgtlen, float* __restrict__ out)
{
    const int b  = blockIdx.x;
    const int l  = threadIdx.x;          // lane 0..63
    const int len = loglen[b];           // in [512, 1024]
    const int tl  = tgtlen[b];           // in [64, 128]

    const int* tg = targets + b * L;
    const int t2l   = tg[2 * l];
    const int t2lm1 = (l > 0) ? tg[2 * l - 1] : -3;
    const int t2lp1 = tg[2 * l + 1];
    const bool cs1 = (t2l != t2lm1);     // skip into s=4l+1
    const bool cs3 = (t2lp1 != t2l);     // skip into s=4l+3

    // t = 0 init (true scale, Se = 0)
    float A0 = (l == 0) ? pB[(size_t)b * T] : 0.0f;
    float A1 = (l == 0) ? pQ[(size_t)b * T * 128] : 0.0f;
    float A2 = 0.0f, A3 = 0.0f, A4 = 0.0f;
    float p3 = 0.0f;                     // alpha[4l-1] carried from prev step
    int Se = 0;                          // accumulated log2 of removed scale

    __shared__ __align__(16) float sQ[2][TS][128];   // 64 KB
    __shared__ __align__(16) float sB[2][TS];
    __shared__ float alpha[S];

    // per-lane global base for staged label rows
    const float* gQ = pQ + (size_t)b * T * 128 + (l & 31) * 4;

    #define STAGE(buf, t0)                                                     \
    {                                                                          \
        _Pragma("unroll")                                                      \
        for (int c = 0; c < TS / 2; ++c) {                                     \
            const int r  = (t0) + 2 * c + (l >> 5);                            \
            const int rc = (r < T) ? r : (T - 1);                              \
            const float* gp = gQ + (size_t)rc * 128;                           \
            __builtin_amdgcn_global_load_lds(                                  \
                (const __attribute__((address_space(1))) void*)gp,             \
                (__attribute__((address_space(3))) void*)&sQ[buf][2 * c][0],   \
                16, 0, 0);                                                     \
        }                                                                      \
        {                                                                      \
            const int r  = (t0) + l;                                           \
            const int rc = (r < T) ? r : (T - 1);                              \
            const float* gp = pB + (size_t)b * T + rc;                         \
            __builtin_amdgcn_global_load_lds(                                  \
                (const __attribute__((address_space(1))) void*)gp,             \
                (__attribute__((address_space(3))) void*)&sB[buf][0],          \
                4, 0, 0);                                                      \
        }                                                                      \
    }

    // two 8-step register group buffers (all indices compile-time constants)
    float2 qa[8]; float ba[8];
    float2 qb[8]; float bbf[8];

    #define LOADG(QD, BD, cbuf, r0)                                            \
    {                                                                          \
        _Pragma("unroll")                                                      \
        for (int r = 0; r < 8; ++r) {                                          \
            QD[r] = *reinterpret_cast<const float2*>(&sQ[cbuf][(r0) + r][2*l]);\
            BD[r] = sB[cbuf][(r0) + r];                                        \
        }                                                                      \
    }

    #define STEP_ONE(pb, p1, pl3)                                              \
    {                                                                          \
        const float n0 = (A0 + p3) * (pb);                                     \
        const float n1 = (A1 + A0 + (cs1 ? p3 : 0.0f)) * (p1);                 \
        const float n2 = (A2 + A1) * (pb);                                     \
        const float n3 = (A3 + A2 + (cs3 ? A1 : 0.0f)) * (pl3);                \
        const float n4 = (A4 + A3) * (pb);                                     \
        A0 = n0; A1 = n1; A2 = n2; A3 = n3; A4 = n4;                           \
        p3 = dpp_mov<0x138>(0.0f, A3);     /* wave_shr:1, lane0 <- 0 */        \
    }

    // wave-uniform power-of-2 rescale: normalize max toward 2^120
    #define RESCALE()                                                          \
    {                                                                          \
        float m_ = fmaxf(fmaxf(A0, A1), fmaxf(A2, fmaxf(A3, A4)));             \
        m_ = fmaxf(m_, dpp_mov<0x111>(m_, m_));   /* row_shr:1  */             \
        m_ = fmaxf(m_, dpp_mov<0x112>(m_, m_));   /* row_shr:2  */             \
        m_ = fmaxf(m_, dpp_mov<0x114>(m_, m_));   /* row_shr:4  */             \
        m_ = fmaxf(m_, dpp_mov<0x118>(m_, m_));   /* row_shr:8  */             \
        m_ = fmaxf(m_, dpp_mov<0x142>(m_, m_));   /* row_bcast:15 */           \
        m_ = fmaxf(m_, dpp_mov<0x143>(m_, m_));   /* row_bcast:31 */           \
        const int e = (__builtin_amdgcn_readlane(__float_as_int(m_), 63)       \
                       >> 23) & 0xff;                                          \
        int kb = 374 - e;                  /* scale = 2^(247-e), biased */     \
        if (kb > 254) kb = 254;            /* clamp, self-recovers */          \
        const float sc = __int_as_float(kb << 23);                             \
        A0 *= sc; A1 *= sc; A2 *= sc; A3 *= sc; A4 *= sc; p3 *= sc;            \
        Se -= (kb - 127);                                                      \
    }

    STAGE(0, 1);                         // prologue: rows 1..TS -> buf 0
    int cb = 0;

    int tb = 1;
    for (; tb + TS <= len; tb += TS) {   // full blocks, no per-step guards
        asm volatile("s_waitcnt vmcnt(0)" ::: "memory");
        STAGE(cb ^ 1, tb + TS);
        LOADG(qa, ba, cb, 0);            // group 0
        #pragma unroll
        for (int g = 0; g < 8; ++g) {    // g is compile-time under unroll
            if (g < 7) {                 // prefetch group g+1 into other buffer
                if (g & 1) { LOADG(qa, ba, cb, (g + 1) * 8); }
                else       { LOADG(qb, bbf, cb, (g + 1) * 8); }
            }
            #pragma unroll
            for (int i = 0; i < 8; ++i) {
                if (g & 1) { STEP_ONE(bbf[i], qb[i].x, qb[i].y); }
                else       { STEP_ONE(ba[i],  qa[i].x, qa[i].y); }
            }
            RESCALE();
        }
        cb ^= 1;
    }
    if (tb < len) {                      // guarded tail block
        asm volatile("s_waitcnt vmcnt(0)" ::: "memory");
        LOADG(qa, ba, cb, 0);
        #pragma unroll
        for (int g = 0; g < 8; ++g) {
            if (g < 7) {
                if (g & 1) { LOADG(qa, ba, cb, (g + 1) * 8); }
                else       { LOADG(qb, bbf, cb, (g + 1) * 8); }
            }
            #pragma unroll
            for (int i = 0; i < 8; ++i) {
                if (tb + g * 8 + i < len) {      // wave-uniform freeze
                    if (g & 1) { STEP_ONE(bbf[i], qb[i].x, qb[i].y); }
                    else       { STEP_ONE(ba[i],  qa[i].x, qa[i].y); }
                }
            }
            if (tb + g * 8 + 7 < len) RESCALE();
        }
    }
    #undef STEP_ONE
    #undef RESCALE
    #undef LOADG
    #undef STAGE

    alpha[4 * l + 0] = A0;
    alpha[4 * l + 1] = A1;
    alpha[4 * l + 2] = A2;
    alpha[4 * l + 3] = A3;
    if (l == 63) alpha[256] = A4;
    __syncthreads();

    if (l == 0) {
        const float sum = alpha[2 * tl] + alpha[2 * tl - 1];
        out[b] = -LN2 * (flog2(sum) + (float)Se);
    }
}

extern "C" void kernel_launch(void* const* d_in, const int* in_sizes, int n_in,
                              void* d_out, int out_size, void* d_ws, size_t ws_size,
                              hipStream_t stream) {
    const float* logits  = (const float*)d_in[0];
    const int*   targets = (const int*)d_in[1];
    const int*   loglen  = (const int*)d_in[2];
    const int*   tgtlen  = (const int*)d_in[3];
    float* out = (float*)d_out;
    float* pQ = (float*)d_ws;                                // B*T*128 floats
    float* pB = pQ + (size_t)B * T * 128;                    // B*T floats

    k_lse_gather<<<B * T, 256, 0, stream>>>(logits, targets, tgtlen, pQ, pB);
    k_ctc_alpha<<<B, 64, 0, stream>>>(pQ, pB, targets, loglen, tgtlen, out);
}